// Round 6
// baseline (56746.338 us; speedup 1.0000x reference)
//
#include <hip/hip_runtime.h>

// ---------------------------------------------------------------------------
// 2-layer LSTM (B=4096, H=512, T=100) + per-step FC(63), fp16 MFMA.
// 32 teams (128 batch rows) x 8 blocks (64 hidden units / j-slice).
// h-state and weights live in pre-swizzled 16KB/32KB "chunk images";
// staging is global_load_lds DMA into a 3-deep LDS ring with counted
// vmcnt(6) + raw s_barrier per chunk (no vmcnt(0) in the loop).
// Team barrier replaced by per-slice producer/consumer flags (release
// atomics + acquire fences); chunks consumed in rotated order (own slice
// first). Lagged 'done' counter bounds skew for the 3-parity h buffers.
// ---------------------------------------------------------------------------

#define HIDN  512
#define SEQL  100
#define BATCH 4096
#define NB    8
#define BR    128

typedef _Float16 f16;
typedef _Float16 half8 __attribute__((ext_vector_type(8)));
typedef float    f32x4 __attribute__((ext_vector_type(4)));
typedef unsigned int u32x4 __attribute__((ext_vector_type(4)));

// ws layout (bytes)
#define OFF_XCAT   0ul                                   // 256*4096*4
#define OFF_X0F    (OFF_XCAT + 256ul*4096*4)             // 2048*4096*4 (frag layout)
#define OFF_W0     (OFF_X0F  + 2048ul*4096*4)            // 2MB chunk-image layout
#define OFF_W1I    (OFF_W0   + 2048ul*512*2)
#define OFF_W1H    (OFF_W1I  + 2048ul*512*2)
#define OFF_FCF    (OFF_W1H  + 2048ul*512*2)             // 64*512*2 (frag layout)
#define OFF_B1P    (OFF_FCF  + 64ul*512*2)               // 2048*4
#define OFF_H0     (OFF_B1P  + 2048ul*4)                 // 3 parities x 4MB images
#define OFF_H1     (OFF_H0   + 3ul*4096*512*2)
#define OFF_FLAGS  (OFF_H1   + 3ul*4096*512*2)           // f0[32][8] f1[32][8] done[32]
#define FLAG_BYTES (544ul*4)

#define HP 4194304ul   // h bytes per parity (32 teams * 128KB)
#define HT 131072ul    // h bytes per team
#define HC 16384ul     // h bytes per chunk (128 rows * 64 k * 2B)
#define WCB 32768ul    // weight image bytes per chunk (256 rows * 64 k * 2B)

// packed row pr = j*256 + g*64 + u  ->  original gate row g*512 + j*64 + u
__device__ __forceinline__ int orow(int pr){
  return (((pr>>6)&3)<<9) | ((pr>>8)<<6) | (pr&63);
}
__device__ __forceinline__ float sigm(float x){ return 1.f/(1.f + __expf(-x)); }
__device__ __forceinline__ float tanhx(float x){ return 1.f - 2.f/(1.f + __expf(2.f*x)); }
__device__ __forceinline__ f32x4 splat4(float v){ f32x4 r; r[0]=v; r[1]=v; r[2]=v; r[3]=v; return r; }

// 16B global->LDS DMA (wave-uniform LDS base + lane*16)
__device__ __forceinline__ void dma16(const void* g, void* l){
  __builtin_amdgcn_global_load_lds(
      (const __attribute__((address_space(1))) unsigned int*)g,
      (__attribute__((address_space(3))) unsigned int*)l, 16, 0, 0);
}

// ---------------- prep 1: xcatT[c][b] ----------------
__global__ __launch_bounds__(256) void k_xcat(
    const int* __restrict__ sl, const int* __restrict__ el,
    const float* __restrict__ sc, const float* __restrict__ ec,
    const float* __restrict__ emb, float* __restrict__ xcatT)
{
  int b = blockIdx.x*256 + threadIdx.x;
  int c = blockIdx.y;
  float v = 0.f;
  if      (c < 64 ) v = emb[sl[b]*64 + c];
  else if (c < 128) v = emb[el[b]*64 + (c-64)];
  else if (c < 191) v = sc[b*63 + (c-128)];
  else if (c < 254) v = ec[b*63 + (c-191)];
  xcatT[c*4096 + b] = v;
}

// ---------------- prep 2: weights -> swizzled chunk images; fcF; biases ------
// image byte for (row r, k): r*128 + (((k>>3) ^ (r&7))<<4) + (k&7)*2
__global__ __launch_bounds__(256) void k_pack(
    const float* __restrict__ Whh0, const float* __restrict__ Wih1,
    const float* __restrict__ Whh1, const float* __restrict__ fcW,
    const float* __restrict__ bih1, const float* __restrict__ bhh1,
    char* __restrict__ W0, char* __restrict__ W1i, char* __restrict__ W1h,
    f16* __restrict__ fcF, float* __restrict__ b1p)
{
  int bx = blockIdx.x, t = threadIdx.x;
  if (bx < 192){
    int m   = bx / 64;             // 0:Whh0 1:Wih1 2:Whh1
    int rem = bx % 64;
    int jj = rem >> 3, kc = rem & 7;
    const float* src = (m==0) ? Whh0 : (m==1) ? Wih1 : Whh1;
    char* dst = ((m==0) ? W0 : (m==1) ? W1i : W1h) + (size_t)(jj*8 + kc)*WCB;
    int r = t;                     // 256 rows
    int orig = orow(jj*256 + r);
    const float* sp = src + (size_t)orig*512 + kc*64;
    char* drow = dst + r*128;
#pragma unroll
    for (int s=0; s<8; s++){
      half8 tmp;
#pragma unroll
      for (int e=0; e<8; e++) tmp[e] = (f16)sp[s*8 + e];
      *(half8*)(drow + ((s ^ (r&7))<<4)) = tmp;
    }
  } else if (bx < 196){
    int wc = bx - 192;
    for (int s=0; s<4; s++){
      int pid = t + s*256;
      int kc = pid >> 6, lane = pid & 63;
      int lcc = lane & 15, qd = lane >> 4;
      int col = wc*16 + lcc;
      f16* d = fcF + (size_t)(wc*16 + kc)*512 + lane*8;
      if (col < 63){
        const float* sp = fcW + (size_t)col*512 + kc*32 + qd*8;
#pragma unroll
        for (int e=0; e<8; e++) d[e] = (f16)sp[e];
      } else {
#pragma unroll
        for (int e=0; e<8; e++) d[e] = (f16)0.f;
      }
    }
  } else {
    int jj = bx - 196;
    int orig = (((t>>6)&3)<<9) | (jj<<6) | (t&63);
    b1p[jj*256 + t] = bih1[orig] + bhh1[orig];
  }
}

// ---------------- prep 3: x0 fragment layout (unchanged) ---------------------
__global__ __launch_bounds__(256) void k_x0(
    const float* __restrict__ xcatT, const float* __restrict__ Wih0,
    const float* __restrict__ bih0, const float* __restrict__ bhh0,
    float* __restrict__ x0F)
{
  int pr0 = blockIdx.x * 16;
  int b   = blockIdx.y * 256 + threadIdx.x;
  float a[16];
#pragma unroll
  for (int i=0;i<16;i++) a[i] = 0.f;
  for (int k=0;k<254;k++){
    float xv = xcatT[k*4096 + b];
#pragma unroll
    for (int i=0;i<16;i++)
      a[i] = fmaf(xv, Wih0[orow(pr0+i)*254 + k], a[i]);
  }
  int team = b>>7, wrr = (b>>6)&1, mtt = (b>>4)&3, qd = (b>>2)&3, r = b&3;
#pragma unroll
  for (int i=0;i<16;i++){
    int pr = pr0 + i;
    int orig = orow(pr);
    int jj = pr>>8, g = (pr>>6)&3, u = pr&63, wcc = u>>4, lcc = u&15;
    size_t idx = (size_t)team*262144 + (size_t)jj*32768 + g*8192 + wrr*4096
               + mtt*1024 + wcc*256 + (qd*16 + lcc)*4 + r;
    x0F[idx] = a[i] + bih0[orig] + bhh0[orig];
  }
}

// ---------------- main persistent LSTM kernel --------------------------------
__global__ __launch_bounds__(512, 1) void k_lstm(
    const float* __restrict__ x0F, const char* __restrict__ W0,
    const char* __restrict__ W1i, const char* __restrict__ W1h,
    const f16* __restrict__ fcF, const float* __restrict__ b1p,
    const float* __restrict__ fcb, char* __restrict__ h0img,
    char* __restrict__ h1img, unsigned int* __restrict__ flags,
    float* __restrict__ out)
{
  __shared__ char Ab[3*16384];   // 3-deep A chunk ring (48 KB)
  __shared__ char Bb[3*32768];   // 3-deep B chunk ring (96 KB)

  const int tid  = threadIdx.x;
  const int blk  = blockIdx.x;
  const int j    = blk & 7;
  const int team = blk >> 3;
  const int b0   = team * BR;
  const int w = tid >> 6, wr = w >> 2, wc = w & 3;
  const int lane = tid & 63, quad = lane >> 4, lc = lane & 15;
  const int ucol = wc*16 + lc;
  const bool des = (j == (team & 7));
  const int rsw = lc & 7;

  const char* Wb0  = W0  + (size_t)j*8*WCB;
  const char* Wb1i = W1i + (size_t)j*8*WCB;
  const char* Wb1h = W1h + (size_t)j*8*WCB;
  const f16* fcp = fcF + (size_t)(wc*16)*512 + lane*8;
  const float* x0p = x0F + (size_t)team*262144 + (size_t)j*32768
                   + wr*4096 + wc*256 + lane*4;

  unsigned int* f0 = flags + team*8;
  unsigned int* f1 = flags + 256 + team*8;
  unsigned int* dn = flags + 512 + team;

  float b1v[4];
#pragma unroll
  for (int g=0; g<4; g++) b1v[g] = b1p[j*256 + g*64 + ucol];
  const float fcbv = (ucol < 63) ? fcb[ucol] : 0.f;

  f32x4 c0[4], c1[4];
#pragma unroll
  for (int mt=0; mt<4; mt++){ c0[mt] = splat4(0.f); c1[mt] = splat4(0.f); }

  f32x4 acc[4][4];
  f32x4 fca[4];

  // flag wait + acquire (invalidate stale cached h before DMA reads)
  auto POLLA = [&](unsigned int* f, unsigned tgt){
    while (__hip_atomic_load(f, __ATOMIC_RELAXED, __HIP_MEMORY_SCOPE_AGENT) < tgt)
      __builtin_amdgcn_s_sleep(2);
    __builtin_amdgcn_fence(__ATOMIC_ACQUIRE, "agent");
  };
  auto POLLW = [&](unsigned int* f, unsigned tgt){   // WAR wait, no acquire
    while (__hip_atomic_load(f, __ATOMIC_RELAXED, __HIP_MEMORY_SCOPE_AGENT) < tgt)
      __builtin_amdgcn_s_sleep(2);
  };

  // stage one chunk: A image 16KB + B image 32KB, wave w's segments (6 DMAs)
  auto STAGE = [&](int d, const char* Ag, const char* Bg){
    const char* ga = Ag + w*2048 + lane*16;
    const char* gb = Bg + w*4096 + lane*16;
#pragma unroll
    for (int c=0; c<2; c++) dma16(ga + c*1024, Ab + d*16384 + w*2048 + c*1024);
#pragma unroll
    for (int c=0; c<4; c++) dma16(gb + c*1024, Bb + d*32768 + w*4096 + c*1024);
  };

  // compute one K=64 chunk from ring slot d; fcs>=0: fuse fc for k-slice fcs
  auto CHUNK = [&](int d, int fcs){
    const char* Ad = Ab + d*16384;
    const char* Bd = Bb + d*32768;
#pragma unroll
    for (int kq=0; kq<2; kq++){
      const int sa = ((kq*4 + quad) ^ rsw) * 16;
      half8 af[4], bf[4];
#pragma unroll
      for (int mt=0; mt<4; mt++)
        af[mt] = *(const half8*)(Ad + (wr*64 + mt*16 + lc)*128 + sa);
#pragma unroll
      for (int g=0; g<4; g++)
        bf[g] = *(const half8*)(Bd + (g*64 + wc*16 + lc)*128 + sa);
#pragma unroll
      for (int g=0; g<4; g++)
#pragma unroll
        for (int mt=0; mt<4; mt++)
          acc[g][mt] = __builtin_amdgcn_mfma_f32_16x16x32_f16(af[mt], bf[g], acc[g][mt], 0, 0, 0);
      if (fcs >= 0){
        half8 fb = *(const half8*)(fcp + (size_t)(fcs*2 + kq)*512);
#pragma unroll
        for (int mt=0; mt<4; mt++)
          fca[mt] = __builtin_amdgcn_mfma_f32_16x16x32_f16(af[mt], fb, fca[mt], 0, 0, 0);
      }
    }
  };

  // pipelined pass: 3-deep ring, counted vmcnt, one raw barrier per chunk
  auto PASS = [&](int NCH, auto&& AG, auto&& BG, auto&& FL, auto&& TG, auto&& FCS){
    __builtin_amdgcn_s_barrier();           // ring reuse guard vs previous pass
    asm volatile("" ::: "memory");
    POLLA(FL(0), TG(0)); STAGE(0, AG(0), BG(0));
    POLLA(FL(1), TG(1)); STAGE(1, AG(1), BG(1));
    for (int kc=0; kc<NCH; kc++){
      if (kc == NCH-1) asm volatile("s_waitcnt vmcnt(0)" ::: "memory");
      else             asm volatile("s_waitcnt vmcnt(6)" ::: "memory");
      __builtin_amdgcn_s_barrier();
      asm volatile("" ::: "memory");
      if (kc+2 < NCH){
        POLLA(FL(kc+2), TG(kc+2));
        STAGE((kc+2)%3, AG(kc+2), BG(kc+2));
      }
      CHUNK(kc%3, FCS(kc));
    }
  };

  // gates + h-image store + per-wave release publish
  auto GATES = [&](f32x4 (&cc)[4], char* img, unsigned int* fl, bool adddone){
#pragma unroll
    for (int mt=0; mt<4; mt++){
#pragma unroll
      for (int r=0; r<4; r++){
        float iv = sigm(acc[0][mt][r]);
        float fv = sigm(acc[1][mt][r]);
        float gv = tanhx(acc[2][mt][r]);
        float ov = sigm(acc[3][mt][r]);
        float cn = fv*cc[mt][r] + iv*gv;
        cc[mt][r] = cn;
        float hn = ov * tanhx(cn);
        int row = wr*64 + mt*16 + quad*4 + r;
        int by  = row*128 + ((((ucol>>3) ^ (row&7))<<4) | ((ucol&7)<<1));
        *(f16*)(img + by) = (f16)hn;
      }
    }
    if (lane == 0){
      __hip_atomic_fetch_add(fl, 1u, __ATOMIC_RELEASE, __HIP_MEMORY_SCOPE_AGENT);
      if (adddone)
        __hip_atomic_fetch_add(dn, 1u, __ATOMIC_RELEASE, __HIP_MEMORY_SCOPE_AGENT);
    }
  };
  auto LOADX0 = [&](){
#pragma unroll
    for (int g=0; g<4; g++)
#pragma unroll
      for (int mt=0; mt<4; mt++)
        acc[g][mt] = __builtin_nontemporal_load(
                       (const f32x4*)(x0p + g*8192 + mt*1024));
  };

  // ================= t = 0 =================
  LOADX0();
  GATES(c0, h0img + team*HT + j*HC, &f0[j], false);       // parity 0
#pragma unroll
  for (int g=0; g<4; g++)
#pragma unroll
    for (int mt=0; mt<4; mt++) acc[g][mt] = splat4(b1v[g]);
  PASS(8,
    [&](int kc){ int jj=(j+kc)&7; return h0img + team*HT + jj*HC; },
    [&](int kc){ int jj=(j+kc)&7; return Wb1i + jj*WCB; },
    [&](int kc){ return &f0[(j+kc)&7]; },
    [&](int kc){ return 8u; },
    [&](int kc){ return -1; });
  GATES(c1, h1img + team*HT + j*HC, &f1[j], true);        // parity 0, done++
  LOADX0();

  // ================= main loop =================
  for (int t=1; t<SEQL; t++){
    const size_t p  = (size_t)(t % 3) * HP;
    const size_t pp = (size_t)((t-1) % 3) * HP;

    // ----- layer 0: acc(preloaded x0) += h0(t-1) @ Whh0^T -----
    PASS(8,
      [&](int kc){ int jj=(j+kc)&7; return h0img + pp + team*HT + jj*HC; },
      [&](int kc){ int jj=(j+kc)&7; return Wb0 + jj*WCB; },
      [&](int kc){ return &f0[(j+kc)&7]; },
      [&](int kc){ return (unsigned)(8*t); },
      [&](int kc){ return -1; });
    if (t >= 2) POLLW(dn, (unsigned)(64*(t-1)));          // WAR: parity reuse
    GATES(c0, h0img + p + team*HT + j*HC, &f0[j], false);

    // ----- layer 1: b1 + h1(t-1)@Whh1^T (kc<8, +fc) + h0(t)@Wih1^T -----
#pragma unroll
    for (int g=0; g<4; g++)
#pragma unroll
      for (int mt=0; mt<4; mt++) acc[g][mt] = splat4(b1v[g]);
#pragma unroll
    for (int mt=0; mt<4; mt++) fca[mt] = splat4(fcbv);

    PASS(16,
      [&](int kc){ if (kc<8){ int jj=(j+kc)&7;   return h1img + pp + team*HT + jj*HC; }
                   else     { int jj=(j+kc-8)&7; return h0img + p  + team*HT + jj*HC; } },
      [&](int kc){ if (kc<8){ int jj=(j+kc)&7;   return Wb1h + jj*WCB; }
                   else     { int jj=(j+kc-8)&7; return Wb1i + jj*WCB; } },
      [&](int kc){ return (kc<8) ? &f1[(j+kc)&7] : &f0[(j+kc-8)&7]; },
      [&](int kc){ return (kc<8) ? (unsigned)(8*t) : (unsigned)(8*(t+1)); },
      [&](int kc){ return (des && kc<8) ? ((j+kc)&7) : -1; });

    if (des && ucol < 63){
#pragma unroll
      for (int mt=0; mt<4; mt++)
#pragma unroll
        for (int r=0; r<4; r++){
          int row = wr*64 + mt*16 + quad*4 + r;
          __builtin_nontemporal_store(fca[mt][r],
              &out[((b0+row)*63 + ucol)*100 + (t-1)]);
        }
    }
    GATES(c1, h1img + p + team*HT + j*HC, &f1[j], true);
    if (t < SEQL-1) LOADX0();
  }

  // ----- epilogue: y(99) from h1(99) (parity 99%3==0), des blocks only -----
  if (des){
#pragma unroll
    for (int mt=0; mt<4; mt++) fca[mt] = splat4(fcbv);
    const char* h1l = h1img + team*HT;    // parity 0
    for (int kc=0; kc<8; kc++){
      POLLA(&f1[kc], 800u);
      const char* ga = h1l + kc*HC + w*2048 + lane*16;
#pragma unroll
      for (int c=0; c<2; c++) dma16(ga + c*1024, Ab + w*2048 + c*1024);
      asm volatile("s_waitcnt vmcnt(0)" ::: "memory");
      __builtin_amdgcn_s_barrier();
      asm volatile("" ::: "memory");
#pragma unroll
      for (int kq=0; kq<2; kq++){
        const int sa = ((kq*4 + quad) ^ rsw) * 16;
        half8 af[4];
#pragma unroll
        for (int mt=0; mt<4; mt++)
          af[mt] = *(const half8*)(Ab + (wr*64 + mt*16 + lc)*128 + sa);
        half8 fb = *(const half8*)(fcp + (size_t)(kc*2 + kq)*512);
#pragma unroll
        for (int mt=0; mt<4; mt++)
          fca[mt] = __builtin_amdgcn_mfma_f32_16x16x32_f16(af[mt], fb, fca[mt], 0, 0, 0);
      }
      __builtin_amdgcn_s_barrier();       // ring slot reuse next iteration
      asm volatile("" ::: "memory");
    }
    if (ucol < 63){
#pragma unroll
      for (int mt=0; mt<4; mt++)
#pragma unroll
        for (int r=0; r<4; r++){
          int row = wr*64 + mt*16 + quad*4 + r;
          __builtin_nontemporal_store(fca[mt][r],
              &out[((b0+row)*63 + ucol)*100 + 99]);
        }
    }
  }
}

// ---------------------------------------------------------------------------
extern "C" void kernel_launch(void* const* d_in, const int* in_sizes, int n_in,
                              void* d_out, int out_size, void* d_ws, size_t ws_size,
                              hipStream_t stream)
{
  const int*   sl   = (const int*)  d_in[0];
  const int*   el   = (const int*)  d_in[1];
  const float* sc   = (const float*)d_in[2];
  const float* ec   = (const float*)d_in[3];
  const float* emb  = (const float*)d_in[4];
  const float* Wih0 = (const float*)d_in[5];
  const float* Whh0 = (const float*)d_in[6];
  const float* bih0 = (const float*)d_in[7];
  const float* bhh0 = (const float*)d_in[8];
  const float* Wih1 = (const float*)d_in[9];
  const float* Whh1 = (const float*)d_in[10];
  const float* bih1 = (const float*)d_in[11];
  const float* bhh1 = (const float*)d_in[12];
  const float* fcW  = (const float*)d_in[13];
  const float* fcb  = (const float*)d_in[14];

  char* ws = (char*)d_ws;
  float* xcatT = (float*)(ws + OFF_XCAT);
  float* x0F   = (float*)(ws + OFF_X0F);
  char*  W0    = ws + OFF_W0;
  char*  W1i   = ws + OFF_W1I;
  char*  W1h   = ws + OFF_W1H;
  f16*   fcF   = (f16*)  (ws + OFF_FCF);
  float* b1p   = (float*)(ws + OFF_B1P);
  char*  h0i   = ws + OFF_H0;
  char*  h1i   = ws + OFF_H1;
  unsigned int* flags = (unsigned int*)(ws + OFF_FLAGS);

  hipMemsetAsync(flags, 0, FLAG_BYTES, stream);
  k_xcat<<<dim3(16, 256), 256, 0, stream>>>(sl, el, sc, ec, emb, xcatT);
  k_pack<<<204, 256, 0, stream>>>(Whh0, Wih1, Whh1, fcW, bih1, bhh1,
                                  W0, W1i, W1h, fcF, b1p);
  k_x0<<<dim3(128, 16), 256, 0, stream>>>(xcatT, Wih0, bih0, bhh0, x0F);
  k_lstm<<<256, 512, 0, stream>>>(x0F, W0, W1i, W1h, fcF, b1p, fcb,
                                  h0i, h1i, flags, (float*)d_out);
}

// Round 7
// 27739.606 us; speedup vs baseline: 2.0457x; 2.0457x over previous
//
#include <hip/hip_runtime.h>

// ---------------------------------------------------------------------------
// 2-layer LSTM (B=4096, H=512, T=100) + per-step FC(63), fp16 MFMA.
// 32 teams (128 batch rows) x 8 blocks (64 hidden units / j-slice).
// h-state and weights in pre-swizzled 16KB/32KB chunk images; staging via
// global_load_lds DMA into a 3-deep LDS ring, counted vmcnt(6) + raw
// s_barrier per chunk (conflict-free, verified R6). Sync: ONE team barrier
// per step (R4's tid==0 atomic barrier) -- per step, one fused 24-chunk GEMM
// phase computes pre1(t) [16 chunks] AND pre0(t+1) [8 chunks], all of whose
// inputs (h0(t), h1(t-1)) were published at the previous barrier.
// ---------------------------------------------------------------------------

#define HIDN  512
#define SEQL  100
#define BATCH 4096
#define NB    8
#define BR    128

typedef _Float16 f16;
typedef _Float16 half8 __attribute__((ext_vector_type(8)));
typedef float    f32x4 __attribute__((ext_vector_type(4)));
typedef unsigned int u32x4 __attribute__((ext_vector_type(4)));

// ws layout (bytes)
#define OFF_XCAT   0ul
#define OFF_X0F    (OFF_XCAT + 256ul*4096*4)
#define OFF_W0     (OFF_X0F  + 2048ul*4096*4)
#define OFF_W1I    (OFF_W0   + 2048ul*512*2)
#define OFF_W1H    (OFF_W1I  + 2048ul*512*2)
#define OFF_FCF    (OFF_W1H  + 2048ul*512*2)
#define OFF_B1P    (OFF_FCF  + 64ul*512*2)
#define OFF_H0     (OFF_B1P  + 2048ul*4)                 // 2 parities x 4MB
#define OFF_H1     (OFF_H0   + 2ul*4096*512*2)
#define OFF_FLAGS  (OFF_H1   + 2ul*4096*512*2)           // 32 teams x 128
#define FLAG_BYTES (32ul*128*4)

#define HP 4194304ul   // h bytes per parity
#define HT 131072ul    // h bytes per team
#define HC 16384ul     // h bytes per chunk (128 rows x 64 k x 2B)
#define WCB 32768ul    // weight image bytes per chunk

__device__ __forceinline__ int orow(int pr){
  return (((pr>>6)&3)<<9) | ((pr>>8)<<6) | (pr&63);
}
__device__ __forceinline__ float sigm(float x){ return 1.f/(1.f + __expf(-x)); }
__device__ __forceinline__ float tanhx(float x){ return 1.f - 2.f/(1.f + __expf(2.f*x)); }
__device__ __forceinline__ f32x4 splat4(float v){ f32x4 r; r[0]=v; r[1]=v; r[2]=v; r[3]=v; return r; }

__device__ __forceinline__ void dma16(const void* g, void* l){
  __builtin_amdgcn_global_load_lds(
      (const __attribute__((address_space(1))) unsigned int*)g,
      (__attribute__((address_space(3))) unsigned int*)l, 16, 0, 0);
}

// ---------------- prep 1: xcatT[c][b] ----------------
__global__ __launch_bounds__(256) void k_xcat(
    const int* __restrict__ sl, const int* __restrict__ el,
    const float* __restrict__ sc, const float* __restrict__ ec,
    const float* __restrict__ emb, float* __restrict__ xcatT)
{
  int b = blockIdx.x*256 + threadIdx.x;
  int c = blockIdx.y;
  float v = 0.f;
  if      (c < 64 ) v = emb[sl[b]*64 + c];
  else if (c < 128) v = emb[el[b]*64 + (c-64)];
  else if (c < 191) v = sc[b*63 + (c-128)];
  else if (c < 254) v = ec[b*63 + (c-191)];
  xcatT[c*4096 + b] = v;
}

// ---------------- prep 2: weights -> swizzled chunk images; fcF; biases ------
// image byte for (row r, k): r*128 + (((k>>3) ^ (r&7))<<4) + (k&7)*2
__global__ __launch_bounds__(256) void k_pack(
    const float* __restrict__ Whh0, const float* __restrict__ Wih1,
    const float* __restrict__ Whh1, const float* __restrict__ fcW,
    const float* __restrict__ bih1, const float* __restrict__ bhh1,
    char* __restrict__ W0, char* __restrict__ W1i, char* __restrict__ W1h,
    f16* __restrict__ fcF, float* __restrict__ b1p)
{
  int bx = blockIdx.x, t = threadIdx.x;
  if (bx < 192){
    int m   = bx / 64;             // 0:Whh0 1:Wih1 2:Whh1
    int rem = bx % 64;
    int jj = rem >> 3, kc = rem & 7;
    const float* src = (m==0) ? Whh0 : (m==1) ? Wih1 : Whh1;
    char* dst = ((m==0) ? W0 : (m==1) ? W1i : W1h) + (size_t)(jj*8 + kc)*WCB;
    int r = t;                     // 256 rows
    int orig = orow(jj*256 + r);
    const float* sp = src + (size_t)orig*512 + kc*64;
    char* drow = dst + r*128;
#pragma unroll
    for (int s=0; s<8; s++){
      half8 tmp;
#pragma unroll
      for (int e=0; e<8; e++) tmp[e] = (f16)sp[s*8 + e];
      *(half8*)(drow + ((s ^ (r&7))<<4)) = tmp;
    }
  } else if (bx < 196){
    int wc = bx - 192;
    for (int s=0; s<4; s++){
      int pid = t + s*256;
      int kc = pid >> 6, lane = pid & 63;
      int lcc = lane & 15, qd = lane >> 4;
      int col = wc*16 + lcc;
      f16* d = fcF + (size_t)(wc*16 + kc)*512 + lane*8;
      if (col < 63){
        const float* sp = fcW + (size_t)col*512 + kc*32 + qd*8;
#pragma unroll
        for (int e=0; e<8; e++) d[e] = (f16)sp[e];
      } else {
#pragma unroll
        for (int e=0; e<8; e++) d[e] = (f16)0.f;
      }
    }
  } else {
    int jj = bx - 196;
    int orig = (((t>>6)&3)<<9) | (jj<<6) | (t&63);
    b1p[jj*256 + t] = bih1[orig] + bhh1[orig];
  }
}

// ---------------- prep 3: x0 fragment layout ---------------------------------
__global__ __launch_bounds__(256) void k_x0(
    const float* __restrict__ xcatT, const float* __restrict__ Wih0,
    const float* __restrict__ bih0, const float* __restrict__ bhh0,
    float* __restrict__ x0F)
{
  int pr0 = blockIdx.x * 16;
  int b   = blockIdx.y * 256 + threadIdx.x;
  float a[16];
#pragma unroll
  for (int i=0;i<16;i++) a[i] = 0.f;
  for (int k=0;k<254;k++){
    float xv = xcatT[k*4096 + b];
#pragma unroll
    for (int i=0;i<16;i++)
      a[i] = fmaf(xv, Wih0[orow(pr0+i)*254 + k], a[i]);
  }
  int team = b>>7, wrr = (b>>6)&1, mtt = (b>>4)&3, qd = (b>>2)&3, r = b&3;
#pragma unroll
  for (int i=0;i<16;i++){
    int pr = pr0 + i;
    int orig = orow(pr);
    int jj = pr>>8, g = (pr>>6)&3, u = pr&63, wcc = u>>4, lcc = u&15;
    size_t idx = (size_t)team*262144 + (size_t)jj*32768 + g*8192 + wrr*4096
               + mtt*1024 + wcc*256 + (qd*16 + lcc)*4 + r;
    x0F[idx] = a[i] + bih0[orig] + bhh0[orig];
  }
}

// ---------------- main persistent LSTM kernel --------------------------------
__global__ __launch_bounds__(512, 2) void k_lstm(
    const float* __restrict__ x0F, const char* __restrict__ W0,
    const char* __restrict__ W1i, const char* __restrict__ W1h,
    const f16* __restrict__ fcF, const float* __restrict__ b1p,
    const float* __restrict__ fcb, char* __restrict__ h0img,
    char* __restrict__ h1img, unsigned int* __restrict__ flags,
    float* __restrict__ out)
{
  __shared__ char Ab[3*16384];   // 3-deep A ring (48 KB)
  __shared__ char Bb[3*32768];   // 3-deep B ring (96 KB)

  const int tid  = threadIdx.x;
  const int blk  = blockIdx.x;
  const int j    = blk & 7;
  const int team = blk >> 3;
  const int b0   = team * BR;
  const int w = tid >> 6, wr = w >> 2, wc = w & 3;
  const int lane = tid & 63, quad = lane >> 4, lc = lane & 15;
  const int ucol = wc*16 + lc;
  const bool des = (j == (team & 7));
  const int rsw = lc & 7;

  const char* Wb0  = W0  + (size_t)j*8*WCB;
  const char* Wb1i = W1i + (size_t)j*8*WCB;
  const char* Wb1h = W1h + (size_t)j*8*WCB;
  const f16* fcp = fcF + (size_t)(wc*16)*512 + lane*8;
  const float* x0p = x0F + (size_t)team*262144 + (size_t)j*32768
                   + wr*4096 + wc*256 + lane*4;

  float b1v[4];
#pragma unroll
  for (int g=0; g<4; g++) b1v[g] = b1p[j*256 + g*64 + ucol];
  const float fcbv = (ucol < 63) ? fcb[ucol] : 0.f;

  f32x4 c0[4], c1[4];
#pragma unroll
  for (int mt=0; mt<4; mt++){ c0[mt] = splat4(0.f); c1[mt] = splat4(0.f); }

  f32x4 acc0[4][4], acc1[4][4], fca[4];

  unsigned int* tflags = flags + team*128;
  auto barrier = [&](int idx){
    __syncthreads();
    if (tid == 0){
      __threadfence();
      __hip_atomic_fetch_add(&tflags[idx], 1u, __ATOMIC_RELAXED, __HIP_MEMORY_SCOPE_AGENT);
      while (__hip_atomic_load(&tflags[idx], __ATOMIC_RELAXED, __HIP_MEMORY_SCOPE_AGENT) < (unsigned)NB)
        __builtin_amdgcn_s_sleep(4);
      __threadfence();
    }
    __syncthreads();
  };

  // stage one chunk (wave w's 1/8 of A 16KB + B 32KB = 6 DMAs)
  auto STAGE = [&](int d, const char* Ag, const char* Bg){
    const char* ga = Ag + w*2048 + lane*16;
    const char* gb = Bg + w*4096 + lane*16;
#pragma unroll
    for (int c=0; c<2; c++) dma16(ga + c*1024, Ab + d*16384 + w*2048 + c*1024);
#pragma unroll
    for (int c=0; c<4; c++) dma16(gb + c*1024, Bb + d*32768 + w*4096 + c*1024);
  };

  // compute one K=64 chunk from ring slot d into accumulator A
  auto CHUNK = [&](int d, f32x4 (&A)[4][4], int fcs){
    const char* Ad = Ab + d*16384;
    const char* Bd = Bb + d*32768;
#pragma unroll
    for (int kq=0; kq<2; kq++){
      const int sa = ((kq*4 + quad) ^ rsw) * 16;
      half8 af[4], bf[4];
#pragma unroll
      for (int mt=0; mt<4; mt++)
        af[mt] = *(const half8*)(Ad + (wr*64 + mt*16 + lc)*128 + sa);
#pragma unroll
      for (int g=0; g<4; g++)
        bf[g] = *(const half8*)(Bd + (g*64 + wc*16 + lc)*128 + sa);
#pragma unroll
      for (int g=0; g<4; g++)
#pragma unroll
        for (int mt=0; mt<4; mt++)
          A[g][mt] = __builtin_amdgcn_mfma_f32_16x16x32_f16(af[mt], bf[g], A[g][mt], 0, 0, 0);
      if (fcs >= 0){
        half8 fb = *(const half8*)(fcp + (size_t)(fcs*2 + kq)*512);
#pragma unroll
        for (int mt=0; mt<4; mt++)
          fca[mt] = __builtin_amdgcn_mfma_f32_16x16x32_f16(af[mt], fb, fca[mt], 0, 0, 0);
      }
    }
  };

  auto GATES = [&](f32x4 (&A)[4][4], f32x4 (&cc)[4], char* img){
#pragma unroll
    for (int mt=0; mt<4; mt++){
#pragma unroll
      for (int r=0; r<4; r++){
        float iv = sigm(A[0][mt][r]);
        float fv = sigm(A[1][mt][r]);
        float gv = tanhx(A[2][mt][r]);
        float ov = sigm(A[3][mt][r]);
        float cn = fv*cc[mt][r] + iv*gv;
        cc[mt][r] = cn;
        float hn = ov * tanhx(cn);
        int row = wr*64 + mt*16 + quad*4 + r;
        int by  = row*128 + ((((ucol>>3) ^ (row&7))<<4) | ((ucol&7)<<1));
        *(f16*)(img + by) = (f16)hn;
      }
    }
  };
  auto LOADX0 = [&](f32x4 (&A)[4][4]){
#pragma unroll
    for (int g=0; g<4; g++)
#pragma unroll
      for (int mt=0; mt<4; mt++)
        A[g][mt] = __builtin_nontemporal_load(
                     (const f32x4*)(x0p + g*8192 + mt*1024));
  };

  // ---- prologue: h0(0) = gates(x0), parity 0 ----
  LOADX0(acc0);
  GATES(acc0, c0, h0img + team*HT + j*HC);
  barrier(0);

  // ---- main loop: one fused 24-chunk phase + one barrier per step ----
  for (int t=0; t<SEQL; t++){
    const char* h0c = h0img + (size_t)(t&1)*HP + team*HT;        // h0(t)
    const char* h1p = h1img + (size_t)((t+1)&1)*HP + team*HT;    // h1(t-1)

#pragma unroll
    for (int g=0; g<4; g++)
#pragma unroll
      for (int mt=0; mt<4; mt++) acc1[g][mt] = splat4(b1v[g]);
#pragma unroll
    for (int mt=0; mt<4; mt++) fca[mt] = splat4(fcbv);
    LOADX0(acc0);                                  // pre0(t+1) starts at x0

    // chunk kc -> role: t>0: [0..7]=h0@W1i/acc1, [8..15]=h1@W1h/acc1+fc,
    //                   [16..23]=h0@W0/acc0.  t==0 (16 chunks): skip h1 half.
    const int NCH = (t==0) ? 16 : 24;
    auto CP = [&](int kc, const char*& Ag, const char*& Bg){
      int cc = (t==0 && kc>=8) ? (kc+8) : kc;
      int s = (j + (cc&7)) & 7;
      if (cc < 8)       { Ag = h0c + s*HC; Bg = Wb1i + s*WCB; }
      else if (cc < 16) { Ag = h1p + s*HC; Bg = Wb1h + s*WCB; }
      else              { Ag = h0c + s*HC; Bg = Wb0  + s*WCB; }
    };
    {
      const char *Ag, *Bg;
      CP(0, Ag, Bg); STAGE(0, Ag, Bg);
      CP(1, Ag, Bg); STAGE(1, Ag, Bg);
    }
    for (int kc=0; kc<NCH; kc++){
      if (kc == NCH-1) asm volatile("s_waitcnt vmcnt(0)" ::: "memory");
      else             asm volatile("s_waitcnt vmcnt(6)" ::: "memory");
      __builtin_amdgcn_s_barrier();
      asm volatile("" ::: "memory");
      if (kc+2 < NCH){
        const char *Ag, *Bg;
        CP(kc+2, Ag, Bg);
        STAGE((kc+2)%3, Ag, Bg);
      }
      int cc = (t==0 && kc>=8) ? (kc+8) : kc;
      int s = (j + (cc&7)) & 7;
      if (cc >= 16)     CHUNK(kc%3, acc0, -1);
      else if (cc >= 8) CHUNK(kc%3, acc1, des ? s : -1);
      else              CHUNK(kc%3, acc1, -1);
    }

    // ---- phase B: gates + publish h1(t), h0(t+1); y(t-1) ----
    GATES(acc1, c1, h1img + (size_t)(t&1)*HP + team*HT + j*HC);
    GATES(acc0, c0, h0img + (size_t)((t+1)&1)*HP + team*HT + j*HC);
    if (des && t >= 1 && ucol < 63){
#pragma unroll
      for (int mt=0; mt<4; mt++)
#pragma unroll
        for (int r=0; r<4; r++){
          int row = wr*64 + mt*16 + quad*4 + r;
          __builtin_nontemporal_store(fca[mt][r],
              &out[((b0+row)*63 + ucol)*100 + (t-1)]);
        }
    }
    barrier(1 + t);
  }

  // ---- epilogue: y(99) from h1(99) (parity 99&1 = 1), des blocks only ----
  if (des){
#pragma unroll
    for (int mt=0; mt<4; mt++) fca[mt] = splat4(fcbv);
    const char* h1l = h1img + HP + team*HT;
    for (int kc=0; kc<8; kc++){
      const char* ga = h1l + kc*HC + w*2048 + lane*16;
#pragma unroll
      for (int c=0; c<2; c++) dma16(ga + c*1024, Ab + w*2048 + c*1024);
      asm volatile("s_waitcnt vmcnt(0)" ::: "memory");
      __builtin_amdgcn_s_barrier();
      asm volatile("" ::: "memory");
#pragma unroll
      for (int kq=0; kq<2; kq++){
        const int sa = ((kq*4 + quad) ^ rsw) * 16;
        half8 af[4];
#pragma unroll
        for (int mt=0; mt<4; mt++)
          af[mt] = *(const half8*)(Ab + (wr*64 + mt*16 + lc)*128 + sa);
        half8 fb = *(const half8*)(fcp + (size_t)(kc*2 + kq)*512);
#pragma unroll
        for (int mt=0; mt<4; mt++)
          fca[mt] = __builtin_amdgcn_mfma_f32_16x16x32_f16(af[mt], fb, fca[mt], 0, 0, 0);
      }
      __builtin_amdgcn_s_barrier();
      asm volatile("" ::: "memory");
    }
    if (ucol < 63){
#pragma unroll
      for (int mt=0; mt<4; mt++)
#pragma unroll
        for (int r=0; r<4; r++){
          int row = wr*64 + mt*16 + quad*4 + r;
          __builtin_nontemporal_store(fca[mt][r],
              &out[((b0+row)*63 + ucol)*100 + 99]);
        }
    }
  }
}

// ---------------------------------------------------------------------------
extern "C" void kernel_launch(void* const* d_in, const int* in_sizes, int n_in,
                              void* d_out, int out_size, void* d_ws, size_t ws_size,
                              hipStream_t stream)
{
  const int*   sl   = (const int*)  d_in[0];
  const int*   el   = (const int*)  d_in[1];
  const float* sc   = (const float*)d_in[2];
  const float* ec   = (const float*)d_in[3];
  const float* emb  = (const float*)d_in[4];
  const float* Wih0 = (const float*)d_in[5];
  const float* Whh0 = (const float*)d_in[6];
  const float* bih0 = (const float*)d_in[7];
  const float* bhh0 = (const float*)d_in[8];
  const float* Wih1 = (const float*)d_in[9];
  const float* Whh1 = (const float*)d_in[10];
  const float* bih1 = (const float*)d_in[11];
  const float* bhh1 = (const float*)d_in[12];
  const float* fcW  = (const float*)d_in[13];
  const float* fcb  = (const float*)d_in[14];

  char* ws = (char*)d_ws;
  float* xcatT = (float*)(ws + OFF_XCAT);
  float* x0F   = (float*)(ws + OFF_X0F);
  char*  W0    = ws + OFF_W0;
  char*  W1i   = ws + OFF_W1I;
  char*  W1h   = ws + OFF_W1H;
  f16*   fcF   = (f16*)  (ws + OFF_FCF);
  float* b1p   = (float*)(ws + OFF_B1P);
  char*  h0i   = ws + OFF_H0;
  char*  h1i   = ws + OFF_H1;
  unsigned int* flags = (unsigned int*)(ws + OFF_FLAGS);

  hipMemsetAsync(flags, 0, FLAG_BYTES, stream);
  k_xcat<<<dim3(16, 256), 256, 0, stream>>>(sl, el, sc, ec, emb, xcatT);
  k_pack<<<204, 256, 0, stream>>>(Whh0, Wih1, Whh1, fcW, bih1, bhh1,
                                  W0, W1i, W1h, fcF, b1p);
  k_x0<<<dim3(128, 16), 256, 0, stream>>>(xcatT, Wih0, bih0, bhh0, x0F);
  k_lstm<<<256, 512, 0, stream>>>(x0F, W0, W1i, W1h, fcF, b1p, fcb,
                                  h0i, h1i, flags, (float*)d_out);
}

// Round 8
// 25765.097 us; speedup vs baseline: 2.2024x; 1.0766x over previous
//
#include <hip/hip_runtime.h>

// ---------------------------------------------------------------------------
// 2-layer LSTM (B=4096, H=512, T=100) + per-step FC(63), fp16 MFMA.
// 32 teams (128 batch rows) x 8 blocks (64 hidden units / j-slice).
// h-state and weights in pre-swizzled 16KB/32KB chunk images; staging via
// global_load_lds DMA into a 3-deep LDS ring, counted vmcnt(6) + raw
// s_barrier per chunk. ONE team barrier per step; fused 24-chunk phase
// computes pre1(t) and pre0(t+1). h publication goes through a 16KB LDS
// transpose buffer (A-ring slot 2) and is written to global as full-line
// coalesced 16B stores -- fixes R7's 70GB write amplification (scattered 2B
// stores + DMA thrash caused ~1 line writeback per 2B store).
// ---------------------------------------------------------------------------

#define HIDN  512
#define SEQL  100
#define BATCH 4096
#define NB    8
#define BR    128

typedef _Float16 f16;
typedef _Float16 half8 __attribute__((ext_vector_type(8)));
typedef float    f32x4 __attribute__((ext_vector_type(4)));
typedef unsigned int u32x4 __attribute__((ext_vector_type(4)));

// ws layout (bytes)
#define OFF_XCAT   0ul
#define OFF_X0F    (OFF_XCAT + 256ul*4096*4)
#define OFF_W0     (OFF_X0F  + 2048ul*4096*4)
#define OFF_W1I    (OFF_W0   + 2048ul*512*2)
#define OFF_W1H    (OFF_W1I  + 2048ul*512*2)
#define OFF_FCF    (OFF_W1H  + 2048ul*512*2)
#define OFF_B1P    (OFF_FCF  + 64ul*512*2)
#define OFF_H0     (OFF_B1P  + 2048ul*4)                 // 2 parities x 4MB
#define OFF_H1     (OFF_H0   + 2ul*4096*512*2)
#define OFF_FLAGS  (OFF_H1   + 2ul*4096*512*2)           // 32 teams x 128
#define FLAG_BYTES (32ul*128*4)

#define HP 4194304ul   // h bytes per parity
#define HT 131072ul    // h bytes per team
#define HC 16384ul     // h bytes per chunk (128 rows x 64 k x 2B)
#define WCB 32768ul    // weight image bytes per chunk

__device__ __forceinline__ int orow(int pr){
  return (((pr>>6)&3)<<9) | ((pr>>8)<<6) | (pr&63);
}
__device__ __forceinline__ float sigm(float x){ return 1.f/(1.f + __expf(-x)); }
__device__ __forceinline__ float tanhx(float x){ return 1.f - 2.f/(1.f + __expf(2.f*x)); }
__device__ __forceinline__ f32x4 splat4(float v){ f32x4 r; r[0]=v; r[1]=v; r[2]=v; r[3]=v; return r; }

__device__ __forceinline__ void dma16(const void* g, void* l){
  __builtin_amdgcn_global_load_lds(
      (const __attribute__((address_space(1))) unsigned int*)g,
      (__attribute__((address_space(3))) unsigned int*)l, 16, 0, 0);
}

// ---------------- prep 1: xcatT[c][b] ----------------
__global__ __launch_bounds__(256) void k_xcat(
    const int* __restrict__ sl, const int* __restrict__ el,
    const float* __restrict__ sc, const float* __restrict__ ec,
    const float* __restrict__ emb, float* __restrict__ xcatT)
{
  int b = blockIdx.x*256 + threadIdx.x;
  int c = blockIdx.y;
  float v = 0.f;
  if      (c < 64 ) v = emb[sl[b]*64 + c];
  else if (c < 128) v = emb[el[b]*64 + (c-64)];
  else if (c < 191) v = sc[b*63 + (c-128)];
  else if (c < 254) v = ec[b*63 + (c-191)];
  xcatT[c*4096 + b] = v;
}

// ---------------- prep 2: weights -> swizzled chunk images; fcF; biases ------
// image byte for (row r, k): r*128 + (((k>>3) ^ (r&7))<<4) + (k&7)*2
__global__ __launch_bounds__(256) void k_pack(
    const float* __restrict__ Whh0, const float* __restrict__ Wih1,
    const float* __restrict__ Whh1, const float* __restrict__ fcW,
    const float* __restrict__ bih1, const float* __restrict__ bhh1,
    char* __restrict__ W0, char* __restrict__ W1i, char* __restrict__ W1h,
    f16* __restrict__ fcF, float* __restrict__ b1p)
{
  int bx = blockIdx.x, t = threadIdx.x;
  if (bx < 192){
    int m   = bx / 64;             // 0:Whh0 1:Wih1 2:Whh1
    int rem = bx % 64;
    int jj = rem >> 3, kc = rem & 7;
    const float* src = (m==0) ? Whh0 : (m==1) ? Wih1 : Whh1;
    char* dst = ((m==0) ? W0 : (m==1) ? W1i : W1h) + (size_t)(jj*8 + kc)*WCB;
    int r = t;                     // 256 rows
    int orig = orow(jj*256 + r);
    const float* sp = src + (size_t)orig*512 + kc*64;
    char* drow = dst + r*128;
#pragma unroll
    for (int s=0; s<8; s++){
      half8 tmp;
#pragma unroll
      for (int e=0; e<8; e++) tmp[e] = (f16)sp[s*8 + e];
      *(half8*)(drow + ((s ^ (r&7))<<4)) = tmp;
    }
  } else if (bx < 196){
    int wc = bx - 192;
    for (int s=0; s<4; s++){
      int pid = t + s*256;
      int kc = pid >> 6, lane = pid & 63;
      int lcc = lane & 15, qd = lane >> 4;
      int col = wc*16 + lcc;
      f16* d = fcF + (size_t)(wc*16 + kc)*512 + lane*8;
      if (col < 63){
        const float* sp = fcW + (size_t)col*512 + kc*32 + qd*8;
#pragma unroll
        for (int e=0; e<8; e++) d[e] = (f16)sp[e];
      } else {
#pragma unroll
        for (int e=0; e<8; e++) d[e] = (f16)0.f;
      }
    }
  } else {
    int jj = bx - 196;
    int orig = (((t>>6)&3)<<9) | (jj<<6) | (t&63);
    b1p[jj*256 + t] = bih1[orig] + bhh1[orig];
  }
}

// ---------------- prep 3: x0 fragment layout ---------------------------------
__global__ __launch_bounds__(256) void k_x0(
    const float* __restrict__ xcatT, const float* __restrict__ Wih0,
    const float* __restrict__ bih0, const float* __restrict__ bhh0,
    float* __restrict__ x0F)
{
  int pr0 = blockIdx.x * 16;
  int b   = blockIdx.y * 256 + threadIdx.x;
  float a[16];
#pragma unroll
  for (int i=0;i<16;i++) a[i] = 0.f;
  for (int k=0;k<254;k++){
    float xv = xcatT[k*4096 + b];
#pragma unroll
    for (int i=0;i<16;i++)
      a[i] = fmaf(xv, Wih0[orow(pr0+i)*254 + k], a[i]);
  }
  int team = b>>7, wrr = (b>>6)&1, mtt = (b>>4)&3, qd = (b>>2)&3, r = b&3;
#pragma unroll
  for (int i=0;i<16;i++){
    int pr = pr0 + i;
    int orig = orow(pr);
    int jj = pr>>8, g = (pr>>6)&3, u = pr&63, wcc = u>>4, lcc = u&15;
    size_t idx = (size_t)team*262144 + (size_t)jj*32768 + g*8192 + wrr*4096
               + mtt*1024 + wcc*256 + (qd*16 + lcc)*4 + r;
    x0F[idx] = a[i] + bih0[orig] + bhh0[orig];
  }
}

// ---------------- main persistent LSTM kernel --------------------------------
__global__ __launch_bounds__(512, 2) void k_lstm(
    const float* __restrict__ x0F, const char* __restrict__ W0,
    const char* __restrict__ W1i, const char* __restrict__ W1h,
    const f16* __restrict__ fcF, const float* __restrict__ b1p,
    const float* __restrict__ fcb, char* __restrict__ h0img,
    char* __restrict__ h1img, unsigned int* __restrict__ flags,
    float* __restrict__ out)
{
  __shared__ char Ab[3*16384];   // 3-deep A ring (48 KB); slot 2 doubles as h-stage
  __shared__ char Bb[3*32768];   // 3-deep B ring (96 KB)

  const int tid  = threadIdx.x;
  const int blk  = blockIdx.x;
  const int j    = blk & 7;
  const int team = blk >> 3;
  const int b0   = team * BR;
  const int w = tid >> 6, wr = w >> 2, wc = w & 3;
  const int lane = tid & 63, quad = lane >> 4, lc = lane & 15;
  const int ucol = wc*16 + lc;
  const bool des = (j == (team & 7));
  const int rsw = lc & 7;

  const char* Wb0  = W0  + (size_t)j*8*WCB;
  const char* Wb1i = W1i + (size_t)j*8*WCB;
  const char* Wb1h = W1h + (size_t)j*8*WCB;
  const f16* fcp = fcF + (size_t)(wc*16)*512 + lane*8;
  const float* x0p = x0F + (size_t)team*262144 + (size_t)j*32768
                   + wr*4096 + wc*256 + lane*4;

  float b1v[4];
#pragma unroll
  for (int g=0; g<4; g++) b1v[g] = b1p[j*256 + g*64 + ucol];
  const float fcbv = (ucol < 63) ? fcb[ucol] : 0.f;

  f32x4 c0[4], c1[4];
#pragma unroll
  for (int mt=0; mt<4; mt++){ c0[mt] = splat4(0.f); c1[mt] = splat4(0.f); }

  f32x4 acc0[4][4], acc1[4][4], fca[4];

  unsigned int* tflags = flags + team*128;
  auto barrier = [&](int idx){
    __syncthreads();
    if (tid == 0){
      __threadfence();
      __hip_atomic_fetch_add(&tflags[idx], 1u, __ATOMIC_RELAXED, __HIP_MEMORY_SCOPE_AGENT);
      while (__hip_atomic_load(&tflags[idx], __ATOMIC_RELAXED, __HIP_MEMORY_SCOPE_AGENT) < (unsigned)NB)
        __builtin_amdgcn_s_sleep(4);
      __threadfence();
    }
    __syncthreads();
  };

  // stage one chunk (wave w's 1/8 of A 16KB + B 32KB = 6 DMAs)
  auto STAGE = [&](int d, const char* Ag, const char* Bg){
    const char* ga = Ag + w*2048 + lane*16;
    const char* gb = Bg + w*4096 + lane*16;
#pragma unroll
    for (int c=0; c<2; c++) dma16(ga + c*1024, Ab + d*16384 + w*2048 + c*1024);
#pragma unroll
    for (int c=0; c<4; c++) dma16(gb + c*1024, Bb + d*32768 + w*4096 + c*1024);
  };

  // compute one K=64 chunk from ring slot d into accumulator A
  auto CHUNK = [&](int d, f32x4 (&A)[4][4], int fcs){
    const char* Ad = Ab + d*16384;
    const char* Bd = Bb + d*32768;
#pragma unroll
    for (int kq=0; kq<2; kq++){
      const int sa = ((kq*4 + quad) ^ rsw) * 16;
      half8 af[4], bf[4];
#pragma unroll
      for (int mt=0; mt<4; mt++)
        af[mt] = *(const half8*)(Ad + (wr*64 + mt*16 + lc)*128 + sa);
#pragma unroll
      for (int g=0; g<4; g++)
        bf[g] = *(const half8*)(Bd + (g*64 + wc*16 + lc)*128 + sa);
#pragma unroll
      for (int g=0; g<4; g++)
#pragma unroll
        for (int mt=0; mt<4; mt++)
          A[g][mt] = __builtin_amdgcn_mfma_f32_16x16x32_f16(af[mt], bf[g], A[g][mt], 0, 0, 0);
      if (fcs >= 0){
        half8 fb = *(const half8*)(fcp + (size_t)(fcs*2 + kq)*512);
#pragma unroll
        for (int mt=0; mt<4; mt++)
          fca[mt] = __builtin_amdgcn_mfma_f32_16x16x32_f16(af[mt], fb, fca[mt], 0, 0, 0);
      }
    }
  };

  // gates -> LDS h-stage (Ab slot 2), final swizzled image layout
  auto GATES = [&](f32x4 (&A)[4][4], f32x4 (&cc)[4]){
    char* Hs = Ab + 2*16384;
#pragma unroll
    for (int mt=0; mt<4; mt++){
#pragma unroll
      for (int r=0; r<4; r++){
        float iv = sigm(A[0][mt][r]);
        float fv = sigm(A[1][mt][r]);
        float gv = tanhx(A[2][mt][r]);
        float ov = sigm(A[3][mt][r]);
        float cn = fv*cc[mt][r] + iv*gv;
        cc[mt][r] = cn;
        float hn = ov * tanhx(cn);
        int row = wr*64 + mt*16 + quad*4 + r;
        int by  = row*128 + ((((ucol>>3) ^ (row&7))<<4) | ((ucol&7)<<1));
        *(f16*)(Hs + by) = (f16)hn;
      }
    }
  };
  // LDS h-stage -> global image, full-line coalesced (each 64B line once)
  auto COPYOUT = [&](char* img){
    const char* Hs = Ab + 2*16384;
    int rr = tid >> 2, uu = (tid & 3) * 16;
    u32x4 v0 = *(const u32x4*)(Hs + rr*128 + uu);
    u32x4 v1 = *(const u32x4*)(Hs + rr*128 + uu + 64);
    *(u32x4*)(img + rr*128 + uu) = v0;
    *(u32x4*)(img + rr*128 + uu + 64) = v1;
  };
  auto LOADX0 = [&](f32x4 (&A)[4][4]){
#pragma unroll
    for (int g=0; g<4; g++)
#pragma unroll
      for (int mt=0; mt<4; mt++)
        A[g][mt] = __builtin_nontemporal_load(
                     (const f32x4*)(x0p + g*8192 + mt*1024));
  };

  // ---- prologue: h0(0) = gates(x0), parity 0 ----
  LOADX0(acc0);
  GATES(acc0, c0);
  __syncthreads();
  COPYOUT(h0img + team*HT + j*HC);
  barrier(0);

  // ---- main loop: one fused 24-chunk phase + one barrier per step ----
  for (int t=0; t<SEQL; t++){
    const char* h0c = h0img + (size_t)(t&1)*HP + team*HT;        // h0(t)
    const char* h1p = h1img + (size_t)((t+1)&1)*HP + team*HT;    // h1(t-1)

#pragma unroll
    for (int g=0; g<4; g++)
#pragma unroll
      for (int mt=0; mt<4; mt++) acc1[g][mt] = splat4(b1v[g]);
#pragma unroll
    for (int mt=0; mt<4; mt++) fca[mt] = splat4(fcbv);
    LOADX0(acc0);                                  // pre0(t+1) starts at x0

    // chunk kc -> role: t>0: [0..7]=h0@W1i/acc1, [8..15]=h1@W1h/acc1+fc,
    //                   [16..23]=h0@W0/acc0.  t==0 (16 chunks): skip h1 half.
    const int NCH = (t==0) ? 16 : 24;
    auto CP = [&](int kc, const char*& Ag, const char*& Bg){
      int cc = (t==0 && kc>=8) ? (kc+8) : kc;
      int s = (j + (cc&7)) & 7;
      if (cc < 8)       { Ag = h0c + s*HC; Bg = Wb1i + s*WCB; }
      else if (cc < 16) { Ag = h1p + s*HC; Bg = Wb1h + s*WCB; }
      else              { Ag = h0c + s*HC; Bg = Wb0  + s*WCB; }
    };
    {
      const char *Ag, *Bg;
      CP(0, Ag, Bg); STAGE(0, Ag, Bg);
      CP(1, Ag, Bg); STAGE(1, Ag, Bg);
    }
    for (int kc=0; kc<NCH; kc++){
      if (kc == NCH-1) asm volatile("s_waitcnt vmcnt(0)" ::: "memory");
      else             asm volatile("s_waitcnt vmcnt(6)" ::: "memory");
      __builtin_amdgcn_s_barrier();
      asm volatile("" ::: "memory");
      if (kc+2 < NCH){
        const char *Ag, *Bg;
        CP(kc+2, Ag, Bg);
        STAGE((kc+2)%3, Ag, Bg);
      }
      int cc = (t==0 && kc>=8) ? (kc+8) : kc;
      int s = (j + (cc&7)) & 7;
      if (cc >= 16)     CHUNK(kc%3, acc0, -1);
      else if (cc >= 8) CHUNK(kc%3, acc1, des ? s : -1);
      else              CHUNK(kc%3, acc1, -1);
    }

    // ---- phase B: gates + publish h1(t), h0(t+1) via LDS stage; y(t-1) ----
    __syncthreads();                       // all waves done with ring slot 2
    GATES(acc1, c1);
    __syncthreads();
    COPYOUT(h1img + (size_t)(t&1)*HP + team*HT + j*HC);
    __syncthreads();                       // h-stage reads done
    GATES(acc0, c0);
    __syncthreads();
    COPYOUT(h0img + (size_t)((t+1)&1)*HP + team*HT + j*HC);
    if (des && t >= 1 && ucol < 63){
#pragma unroll
      for (int mt=0; mt<4; mt++)
#pragma unroll
        for (int r=0; r<4; r++){
          int row = wr*64 + mt*16 + quad*4 + r;
          __builtin_nontemporal_store(fca[mt][r],
              &out[((b0+row)*63 + ucol)*100 + (t-1)]);
        }
    }
    barrier(1 + t);
  }

  // ---- epilogue: y(99) from h1(99) (parity 99&1 = 1), des blocks only ----
  if (des){
#pragma unroll
    for (int mt=0; mt<4; mt++) fca[mt] = splat4(fcbv);
    const char* h1l = h1img + HP + team*HT;
    for (int kc=0; kc<8; kc++){
      const char* ga = h1l + kc*HC + w*2048 + lane*16;
#pragma unroll
      for (int c=0; c<2; c++) dma16(ga + c*1024, Ab + w*2048 + c*1024);
      asm volatile("s_waitcnt vmcnt(0)" ::: "memory");
      __builtin_amdgcn_s_barrier();
      asm volatile("" ::: "memory");
#pragma unroll
      for (int kq=0; kq<2; kq++){
        const int sa = ((kq*4 + quad) ^ rsw) * 16;
        half8 af[4];
#pragma unroll
        for (int mt=0; mt<4; mt++)
          af[mt] = *(const half8*)(Ab + (wr*64 + mt*16 + lc)*128 + sa);
        half8 fb = *(const half8*)(fcp + (size_t)(kc*2 + kq)*512);
#pragma unroll
        for (int mt=0; mt<4; mt++)
          fca[mt] = __builtin_amdgcn_mfma_f32_16x16x32_f16(af[mt], fb, fca[mt], 0, 0, 0);
      }
      __builtin_amdgcn_s_barrier();
      asm volatile("" ::: "memory");
    }
    if (ucol < 63){
#pragma unroll
      for (int mt=0; mt<4; mt++)
#pragma unroll
        for (int r=0; r<4; r++){
          int row = wr*64 + mt*16 + quad*4 + r;
          __builtin_nontemporal_store(fca[mt][r],
              &out[((b0+row)*63 + ucol)*100 + 99]);
        }
    }
  }
}

// ---------------------------------------------------------------------------
extern "C" void kernel_launch(void* const* d_in, const int* in_sizes, int n_in,
                              void* d_out, int out_size, void* d_ws, size_t ws_size,
                              hipStream_t stream)
{
  const int*   sl   = (const int*)  d_in[0];
  const int*   el   = (const int*)  d_in[1];
  const float* sc   = (const float*)d_in[2];
  const float* ec   = (const float*)d_in[3];
  const float* emb  = (const float*)d_in[4];
  const float* Wih0 = (const float*)d_in[5];
  const float* Whh0 = (const float*)d_in[6];
  const float* bih0 = (const float*)d_in[7];
  const float* bhh0 = (const float*)d_in[8];
  const float* Wih1 = (const float*)d_in[9];
  const float* Whh1 = (const float*)d_in[10];
  const float* bih1 = (const float*)d_in[11];
  const float* bhh1 = (const float*)d_in[12];
  const float* fcW  = (const float*)d_in[13];
  const float* fcb  = (const float*)d_in[14];

  char* ws = (char*)d_ws;
  float* xcatT = (float*)(ws + OFF_XCAT);
  float* x0F   = (float*)(ws + OFF_X0F);
  char*  W0    = ws + OFF_W0;
  char*  W1i   = ws + OFF_W1I;
  char*  W1h   = ws + OFF_W1H;
  f16*   fcF   = (f16*)  (ws + OFF_FCF);
  float* b1p   = (float*)(ws + OFF_B1P);
  char*  h0i   = ws + OFF_H0;
  char*  h1i   = ws + OFF_H1;
  unsigned int* flags = (unsigned int*)(ws + OFF_FLAGS);

  hipMemsetAsync(flags, 0, FLAG_BYTES, stream);
  k_xcat<<<dim3(16, 256), 256, 0, stream>>>(sl, el, sc, ec, emb, xcatT);
  k_pack<<<204, 256, 0, stream>>>(Whh0, Wih1, Whh1, fcW, bih1, bhh1,
                                  W0, W1i, W1h, fcF, b1p);
  k_x0<<<dim3(128, 16), 256, 0, stream>>>(xcatT, Wih0, bih0, bhh0, x0F);
  k_lstm<<<256, 512, 0, stream>>>(x0F, W0, W1i, W1h, fcF, b1p, fcb,
                                  h0i, h1i, flags, (float*)d_out);
}